// Round 6
// baseline (407.130 us; speedup 1.0000x reference)
//
#include <hip/hip_runtime.h>

#define UNITS   114
#define SDIM    64
#define ACT     18
#define TSTEPS  64

// Bin-packed slots (placement identical to R1):
//   rec: E <= 704 edges, C=13/lane, <=2 posts/lane, <=3 lanes/post.
//   sensory: E == 512, C=9.
#define CR 13
#define CS 9
#define MSTRIDE 24

// 2-wave split of the 13 rec slots: w0 owns slots 0..NR0-1, w1 the rest.
#define NR0 8
#define NR1 (CR - NR0)   // 5

#define LOG2E 1.4426950408889634f
#define EPS   1e-8f

typedef float v2f __attribute__((ext_vector_type(2)));
__device__ __forceinline__ v2f fma2(v2f a, v2f b, v2f c) {
  return __builtin_elementwise_fma(a, b, c);
}
__device__ __forceinline__ float bperm(int addr, float v) {
  return __int_as_float(__builtin_amdgcn_ds_bpermute(addr, __float_as_int(v)));
}
__device__ __forceinline__ float dperm(int addr, float v) {   // push: lane[addr>>2] <- v
  return __int_as_float(__builtin_amdgcn_ds_permute(addr, __float_as_int(v)));
}
__device__ __forceinline__ void wsync() {
  __builtin_amdgcn_fence(__ATOMIC_ACQ_REL, "wavefront");
  __builtin_amdgcn_wave_barrier();
}
__device__ __forceinline__ int canonLane(int u) { return (u >= 64) ? (u - 64) : u; }

// k-th set bit of a 64-bit mask (k 0-based).
__device__ __forceinline__ int kthSetBit(unsigned long long m, int k) {
  int pos = 0;
#pragma unroll
  for (int ww = 32; ww >= 1; ww >>= 1) {
    const unsigned long long lowMask = ((1ull << ww) - 1ull);
    const int c = __popcll(m & lowMask);
    if (k >= c) { k -= c; m >>= ww; pos += ww; }
  }
  return pos;
}
__device__ __forceinline__ unsigned long long shfl_u64(unsigned long long v, int src) {
  const int lo = __shfl((int)(unsigned)(v & 0xffffffffull), src);
  const int hi = __shfl((int)(unsigned)(v >> 32), src);
  return ((unsigned long long)(unsigned)hi << 32) | (unsigned)lo;
}

// ---------------------------------------------------------------------------
// Build (R5 verbatim, proven fast + bit-identical tables).
// ---------------------------------------------------------------------------
__global__ __launch_bounds__(64) void build_all(
    const float* __restrict__ w,  const float* __restrict__ mu,
    const float* __restrict__ sigma, const float* __restrict__ erev,
    const float* __restrict__ mask,
    const float* __restrict__ sw, const float* __restrict__ smu,
    const float* __restrict__ ssg, const float* __restrict__ serev,
    const float* __restrict__ smask,
    float4* __restrict__ recP4, float2* __restrict__ recP2, int* __restrict__ recAd,
    float4* __restrict__ senP4, float2* __restrict__ senP2, int* __restrict__ senAd,
    int* __restrict__ meta)
{
  const int l = threadIdx.x;
  const int bid = blockIdx.x;
  __shared__ int degL[64], pF0L[64];
  __shared__ int contIdx[64], contOwn[64], splitRole[64], split2[64], ownP[128];
  __shared__ int rcv[64];

  contIdx[l] = 0; contOwn[l] = 0; splitRole[l] = -1; split2[l] = 0;
  ownP[2*l] = -1; ownP[2*l+1] = -1;

  if (bid < 4) {
    // ================= REC family =================
    unsigned long long cLo = 0ull, cHi = 0ull;
    if (l < 50) {
      for (int base = 0; base < 64; base += 16) {
        float mv[16];
#pragma unroll
        for (int q = 0; q < 16; ++q) mv[q] = mask[(18 + base + q)*UNITS + l];
#pragma unroll
        for (int q = 0; q < 16; ++q) if (mv[q] != 0.f) cLo |= (1ull << (base + q));
      }
      for (int base = 0; base < 32; base += 16) {
        float mv[16];
#pragma unroll
        for (int q = 0; q < 16; ++q) mv[q] = mask[(82 + base + q)*UNITS + l];
#pragma unroll
        for (int q = 0; q < 16; ++q) if (mv[q] != 0.f) cHi |= (1ull << (base + q));
      }
    }
    const int dreg = __popcll(cLo) + __popcll(cHi);
    degL[l] = dreg;
    wsync();
    {
      int lam = 0, f = 0, pc = 0;
      for (int p = 0; p < 50; ++p) {
        const int dd = __shfl(dreg, p);
        if (pc == 2 || f == CR || dd > 3*CR - f) { ++lam; f = 0; pc = 0; }
        if (lam > 63) lam = 63;
        if (l == 0) { pF0L[p] = f; ownP[2*lam + pc] = p; }
        const int owner = lam, role = pc; ++pc;
        const int take = dd < (CR - f) ? dd : (CR - f);
        f += take; int rem = dd - take;
        if (rem > 0) {
          if (l == 0) { splitRole[owner] = role; split2[owner] = (rem > CR) ? 1 : 0; }
          ++lam; if (lam > 63) lam = 63;
          if (l == 0) { contIdx[lam] = 1; contOwn[lam] = owner; }
          pc = 1;
          const int t2 = rem < CR ? rem : CR; f = t2; rem -= t2;
          if (rem > 0) {
            ++lam; if (lam > 63) lam = 63;
            if (l == 0) { contIdx[lam] = 2; contOwn[lam] = owner; }
            pc = 1; f = rem;
          }
        }
      }
    }
    wsync();
    int dAr = (contIdx[l] == 1) ? contOwn[l] : -1;
    int dBr = (contIdx[l] == 2) ? contOwn[l] : -1;
    rcv[l] = 0; wsync();
    if (dAr >= 0) rcv[dAr] = 1;
    wsync();
    { const unsigned long long rM = __ballot(rcv[l] != 0), dM = __ballot(dAr < 0);
      if (dAr < 0) dAr = kthSetBit(~rM, __popcll(dM & ((1ull << l) - 1ull))); }
    wsync();
    rcv[l] = 0; wsync();
    if (dBr >= 0) rcv[dBr] = 1;
    wsync();
    { const unsigned long long rM = __ballot(rcv[l] != 0), dM = __ballot(dBr < 0);
      if (dBr < 0) dBr = kthSetBit(~rM, __popcll(dM & ((1ull << l) - 1ull))); }
    const int uA = ownP[2*l], uB = ownP[2*l+1];
    if (bid == 0) {
      int* M = meta + l * MSTRIDE;
      M[0] = dAr * 4; M[1] = dBr * 4;
      const float s1A = (splitRole[l] == 0) ? 1.f : 0.f, s1B = (splitRole[l] == 1) ? 1.f : 0.f;
      M[2] = __float_as_int(s1A); M[3] = __float_as_int(s1B);
      const float s2 = split2[l] ? 1.f : 0.f;
      M[4] = __float_as_int(s1A * s2); M[5] = __float_as_int(s1B * s2);
      M[6] = ((uA >= 0) ? uA : 128 + l) * 4;
      M[7] = ((uB >= 0) ? uB : 192 + l) * 4;
      M[8] = (uA >= 0) ? uA : 0;
      M[9] = (uB >= 0) ? uB : 0;
    }
    const int ci = contIdx[l];
    int p1 = -1, br = 0, cnt1 = 0;
    if (ci) {
      const int o = contOwn[l];
      p1 = ownP[2*o + splitRole[o]];
      br = (CR - pF0L[p1]) + ((ci == 2) ? CR : 0);
      cnt1 = degL[p1] - br; if (cnt1 > CR) cnt1 = CR;
    }
    int fA = 0, tA = -1;
    if (uA >= 0) { fA = pF0L[uA]; const int rm = CR - fA; const int dd = degL[uA]; tA = dd < rm ? dd : rm; }
    int fB = 0, tB = -1;
    if (uB >= 0) { fB = pF0L[uB]; const int rm = CR - fB; const int dd = degL[uB]; tB = dd < rm ? dd : rm; }
    for (int s = bid; s < CR; s += 4) {
      int post = -1, rank = 0, isB = 0;
      if (ci && s < cnt1)                          { post = p1; rank = br + s; }
      else if (uA >= 0 && s >= fA && s < fA + tA)  { post = uA; rank = s - fA; }
      else if (uB >= 0 && s >= fB && s < fB + tB)  { post = uB; rank = s - fB; isB = 1; }
      const int postc = (post >= 0) ? post : 0;
      const unsigned long long plo = shfl_u64(cLo, postc);
      const unsigned long long phi = shfl_u64(cHi, postc);
      float4 p4 = make_float4(0.f, 0.f, 0.f, 0.f);
      float2 p2 = make_float2(0.f, 0.f);
      int ad = 0;
      if (post >= 0) {
        const int c = __popcll(plo);
        const int pre = (rank < c) ? (18 + kthSetBit(plo, rank)) : (82 + kthSetBit(phi, rank - c));
        const int idx = pre * UNITS + post;
        const float sg_ = sigma[idx];
        const float nsgl = -sg_ * LOG2E, msl = mu[idx] * sg_ * LOG2E;
        const float wd = w[idx], wn = wd * erev[idx];
        p4 = make_float4(nsgl, msl, isB ? 0.f : wn, isB ? 0.f : wd);
        p2 = isB ? make_float2(wn, wd) : make_float2(0.f, 0.f);
        ad = pre * 4;
      }
      recP4[s*64 + l] = p4; recP2[s*64 + l] = p2; recAd[s*64 + l] = ad;
    }
  } else {
    // ================= SENSORY family =================
    unsigned long long cS = 0ull;
    {
      const int col = 50 + l;
      for (int base = 0; base < 64; base += 16) {
        float mv[16];
#pragma unroll
        for (int q = 0; q < 16; ++q) mv[q] = smask[(base + q)*UNITS + col];
#pragma unroll
        for (int q = 0; q < 16; ++q) if (mv[q] != 0.f) cS |= (1ull << (base + q));
      }
    }
    const int dreg = __popcll(cS);
    degL[l] = dreg;
    wsync();
    {
      int lam = 0, f = 0, pc = 0;
      for (int p = 0; p < 64; ++p) {
        const int dd = __shfl(dreg, p);
        if (pc == 2 || f == CS || dd > 3*CS - f) { ++lam; f = 0; pc = 0; }
        if (lam > 63) lam = 63;
        if (l == 0) { pF0L[p] = f; ownP[2*lam + pc] = p; }
        const int owner = lam, role = pc; ++pc;
        const int take = dd < (CS - f) ? dd : (CS - f);
        f += take; int rem = dd - take;
        if (rem > 0) {
          if (l == 0) { splitRole[owner] = role; split2[owner] = (rem > CS) ? 1 : 0; }
          ++lam; if (lam > 63) lam = 63;
          if (l == 0) { contIdx[lam] = 1; contOwn[lam] = owner; }
          pc = 1;
          const int t2 = rem < CS ? rem : CS; f = t2; rem -= t2;
          if (rem > 0) {
            ++lam; if (lam > 63) lam = 63;
            if (l == 0) { contIdx[lam] = 2; contOwn[lam] = owner; }
            pc = 1; f = rem;
          }
        }
      }
    }
    wsync();
    int dAs = (contIdx[l] == 1) ? contOwn[l] : -1;
    int dBs = (contIdx[l] == 2) ? contOwn[l] : -1;
    rcv[l] = 0; wsync();
    if (dAs >= 0) rcv[dAs] = 1;
    wsync();
    { const unsigned long long rM = __ballot(rcv[l] != 0), dM = __ballot(dAs < 0);
      if (dAs < 0) dAs = kthSetBit(~rM, __popcll(dM & ((1ull << l) - 1ull))); }
    wsync();
    rcv[l] = 0; wsync();
    if (dBs >= 0) rcv[dBs] = 1;
    wsync();
    { const unsigned long long rM = __ballot(rcv[l] != 0), dM = __ballot(dBs < 0);
      if (dBs < 0) dBs = kthSetBit(~rM, __popcll(dM & ((1ull << l) - 1ull))); }
    wsync();
    int rAs = (ownP[2*l]   >= 0) ? canonLane(50 + ownP[2*l])   : -1;
    int rBs = (ownP[2*l+1] >= 0) ? canonLane(50 + ownP[2*l+1]) : -1;
    rcv[l] = 0; wsync();
    if (rAs >= 0) rcv[rAs] = 1;
    wsync();
    const int isRcvA = rcv[l];
    { const unsigned long long rM = __ballot(isRcvA != 0), dM = __ballot(rAs < 0);
      if (rAs < 0) rAs = kthSetBit(~rM, __popcll(dM & ((1ull << l) - 1ull))); }
    wsync();
    rcv[l] = 0; wsync();
    if (rBs >= 0) rcv[rBs] = 1;
    wsync();
    { const unsigned long long rM = __ballot(rcv[l] != 0), dM = __ballot(rBs < 0);
      if (rBs < 0) rBs = kthSetBit(~rM, __popcll(dM & ((1ull << l) - 1ull))); }
    const int pAs = ownP[2*l], pBs = ownP[2*l+1];
    if (bid == 4) {
      int* M = meta + l * MSTRIDE;
      M[10] = dAs * 4; M[11] = dBs * 4;
      const float s1A = (splitRole[l] == 0) ? 1.f : 0.f, s1B = (splitRole[l] == 1) ? 1.f : 0.f;
      M[12] = __float_as_int(s1A); M[13] = __float_as_int(s1B);
      const float s2 = split2[l] ? 1.f : 0.f;
      M[14] = __float_as_int(s1A * s2); M[15] = __float_as_int(s1B * s2);
      M[16] = rAs * 4; M[17] = rBs * 4;
      M[18] = __float_as_int(isRcvA ? 1.f : 0.f);
      M[19] = __float_as_int(isRcvA ? 0.f : 1.f);
      M[20] = (pAs >= 0) ? 50 + pAs : 0;
      M[21] = (pBs >= 0) ? 50 + pBs : 0;
    }
    const int ci = contIdx[l];
    int p1 = -1, br = 0, cnt1 = 0;
    if (ci) {
      const int o = contOwn[l];
      p1 = ownP[2*o + splitRole[o]];
      br = (CS - pF0L[p1]) + ((ci == 2) ? CS : 0);
      cnt1 = degL[p1] - br; if (cnt1 > CS) cnt1 = CS;
    }
    int fA = 0, tA = -1;
    if (pAs >= 0) { fA = pF0L[pAs]; const int rm = CS - fA; const int dd = degL[pAs]; tA = dd < rm ? dd : rm; }
    int fB = 0, tB = -1;
    if (pBs >= 0) { fB = pF0L[pBs]; const int rm = CS - fB; const int dd = degL[pBs]; tB = dd < rm ? dd : rm; }
    for (int s = bid - 4; s < CS; s += 4) {
      int post = -1, rank = 0, isB = 0;
      if (ci && s < cnt1)                            { post = p1;  rank = br + s; }
      else if (pAs >= 0 && s >= fA && s < fA + tA)   { post = pAs; rank = s - fA; }
      else if (pBs >= 0 && s >= fB && s < fB + tB)   { post = pBs; rank = s - fB; isB = 1; }
      const int postc = (post >= 0) ? post : 0;
      const unsigned long long pm = shfl_u64(cS, postc);
      float4 p4 = make_float4(0.f, 0.f, 0.f, 0.f);
      float2 p2 = make_float2(0.f, 0.f);
      int ad = 0;
      if (post >= 0) {
        const int pre = kthSetBit(pm, rank);
        const int idx = pre * UNITS + 50 + post;
        const float sg_ = ssg[idx];
        const float nsgl = -sg_ * LOG2E, msl = smu[idx] * sg_ * LOG2E;
        const float wd = sw[idx], wn = wd * serev[idx];
        p4 = make_float4(nsgl, msl, isB ? 0.f : wn, isB ? 0.f : wd);
        p2 = isB ? make_float2(wn, wd) : make_float2(0.f, 0.f);
        ad = pre * 4;
      }
      senP4[s*64 + l] = p4; senP2[s*64 + l] = p2; senAd[s*64 + l] = ad;
    }
  }
}

// ---------------------------------------------------------------------------
// R15 run: 2 waves per batch element (128 threads).
//   w0 (lanes 0..63):  rec slots 0..7, own-partial dperm-merge, state update,
//                      mirror writes for the 50 rec posts.
//   w1 (lanes 64..127): rec slots 8..12 + own-partial merge -> float4 via LDS,
//                      the whole sensory pipeline, vIn update + write.
// The dperm merge is linear in the accumulator, so each wave merges its own
// partial and w0 just adds w1's float4 contribution after the mid barrier.
// Two barriers per unfold; separate per-wave loops with matched barrier
// counts let the register allocator overlay the two waves' loop state.
// ---------------------------------------------------------------------------
__global__ __launch_bounds__(128, 4) void ltc_run(
    const float* __restrict__ obs,     const float* __restrict__ hidden,
    const float* __restrict__ input_w, const float* __restrict__ input_b,
    const float* __restrict__ gleak,   const float* __restrict__ vleak,
    const float* __restrict__ cm,
    const float* __restrict__ q_w1, const float* __restrict__ q_b1,
    const float* __restrict__ q_w2, const float* __restrict__ q_b2,
    const float4* __restrict__ recP4, const float2* __restrict__ recP2,
    const int* __restrict__ recAd,
    const float4* __restrict__ senP4, const float2* __restrict__ senP2,
    const int* __restrict__ senAd,
    const int* __restrict__ meta, float* __restrict__ out, int B)
{
  const int tid = threadIdx.x, b = blockIdx.x, cl = tid & 63;
  __shared__ float mirror[256];     // [0..113] units, [128..255] sinks
  __shared__ float4 part[64];       // w1 -> w0 merged partial per lane
  __shared__ float4 sw4[CS*64];     // sensory weights {wnA,wdA,wnB,wdB}
  char* mbase = (char*)mirror;

  if (tid < UNITS) mirror[tid] = hidden[(size_t)b*UNITS + tid];
  for (int i = tid; i < CS*64; i += 128) {
    const float4 p4 = senP4[i]; const float2 p2 = senP2[i];
    sw4[i] = make_float4(p4.z, p4.w, p2.x, p2.y);
  }
  const int* M = meta + cl * MSTRIDE;
  // rec merge meta -- needed by BOTH waves (each merges its own partial)
  const int rPush1 = M[0], rPush2 = M[1];
  const v2f gR1A = {__int_as_float(M[2]), __int_as_float(M[2])};
  const v2f gR1B = {__int_as_float(M[3]), __int_as_float(M[3])};
  const v2f gR2A = {__int_as_float(M[4]), __int_as_float(M[4])};
  const v2f gR2B = {__int_as_float(M[5]), __int_as_float(M[5])};
  __syncthreads();

  if (tid < 64) {
    // ==================== WAVE 0 ====================
    float rNS[NR0], rMS[NR0]; v2f rWA[NR0], rWB[NR0]; int rad[NR0];
#pragma unroll
    for (int s = 0; s < NR0; ++s) {
      const float4 p4 = recP4[s*64 + cl]; const float2 p2 = recP2[s*64 + cl];
      rNS[s] = p4.x; rMS[s] = p4.y; rWA[s] = (v2f){p4.z, p4.w};
      rWB[s] = (v2f){p2.x, p2.y}; rad[s] = recAd[s*64 + cl];
    }
    const int rWrA = M[6], rWrB = M[7], rUA = M[8], rUB = M[9];
    const float cmA = cm[rUA]*6.f, glvA = gleak[rUA]*vleak[rUA], cgA = cm[rUA]*6.f + gleak[rUA] + EPS;
    const float cmB = cm[rUB]*6.f, glvB = gleak[rUB]*vleak[rUB], cgB = cm[rUB]*6.f + gleak[rUB] + EPS;
    const bool ownA = (rWrA < 512), ownB = (rWrB < 512);
    const v2f initRA = ownA ? (v2f){glvA, cgA} : (v2f){0.f, EPS};
    const v2f initRB = ownB ? (v2f){glvB, cgB} : (v2f){0.f, EPS};
    float vPA = hidden[(size_t)b*UNITS + rUA];
    float vPB = hidden[(size_t)b*UNITS + rUB];

#pragma unroll 1
    for (int it = 0; it < TSTEPS*6; ++it) {
      __syncthreads();                       // A: all writes of prev unfold visible
      float uu[NR0];
#pragma unroll
      for (int s = 0; s < NR0; ++s) {
        const float pv = *(const float*)(mbase + rad[s]);
        const float z = fmaf(pv, rNS[s], rMS[s]);   // z <= 20.8: no clamp
        uu[s] = 1.f + __builtin_amdgcn_exp2f(z);
      }
      float sg[NR0];
#pragma unroll
      for (int q = 0; q < NR0/2; ++q) {
        const float p = uu[2*q] * uu[2*q+1];
        const float r = __builtin_amdgcn_rcpf(p);
        sg[2*q]   = uu[2*q+1] * r;
        sg[2*q+1] = uu[2*q]   * r;
      }
      v2f a0 = initRA, a1 = {0.f,0.f}, b0 = initRB, b1 = {0.f,0.f};
#pragma unroll
      for (int s = 0; s < NR0; ++s) {
        const v2f s2 = {sg[s], sg[s]};
        if (s & 1) { a1 = fma2(rWA[s], s2, a1); b1 = fma2(rWB[s], s2, b1); }
        else       { a0 = fma2(rWA[s], s2, a0); b0 = fma2(rWB[s], s2, b0); }
      }
      const v2f aA = a0 + a1, aB = b0 + b1;
      const v2f m1 = {dperm(rPush1, aA.x), dperm(rPush1, aA.y)};
      const v2f m2 = {dperm(rPush2, aA.x), dperm(rPush2, aA.y)};
      v2f tA = fma2(gR1A, m1, aA); tA = fma2(gR2A, m2, tA);
      v2f tB = fma2(gR1B, m1, aB); tB = fma2(gR2B, m2, tB);
      __syncthreads();                       // B1: w1's part[] ready
      const float4 pp = part[cl];
      tA = tA + (v2f){pp.x, pp.y};
      tB = tB + (v2f){pp.z, pp.w};
      const float dAq = tA.y, dBq = tB.y;
      const float rr = __builtin_amdgcn_rcpf(dAq * dBq);
      vPA = fmaf(cmA, vPA, tA.x) * (dBq * rr);
      vPB = fmaf(cmB, vPB, tB.x) * (dAq * rr);
      *(float*)(mbase + rWrA) = vPA;
      *(float*)(mbase + rWrB) = vPB;
    }
  } else {
    // ==================== WAVE 1 ====================
    float rNS[NR1], rMS[NR1]; v2f rWA[NR1], rWB[NR1]; int rad[NR1];
#pragma unroll
    for (int s = 0; s < NR1; ++s) {
      const float4 p4 = recP4[(NR0+s)*64 + cl]; const float2 p2 = recP2[(NR0+s)*64 + cl];
      rNS[s] = p4.x; rMS[s] = p4.y; rWA[s] = (v2f){p4.z, p4.w};
      rWB[s] = (v2f){p2.x, p2.y}; rad[s] = recAd[(NR0+s)*64 + cl];
    }
    float sNS[CS], sMS[CS]; int sad[CS];
#pragma unroll
    for (int s = 0; s < CS; ++s) {
      const float4 p4 = senP4[s*64 + cl];
      sNS[s] = p4.x; sMS[s] = p4.y; sad[s] = senAd[s*64 + cl];
    }
    const int sPush1 = M[10], sPush2 = M[11];
    const v2f gS1A = {__int_as_float(M[12]), __int_as_float(M[12])};
    const v2f gS1B = {__int_as_float(M[13]), __int_as_float(M[13])};
    const v2f gS2A = {__int_as_float(M[14]), __int_as_float(M[14])};
    const v2f gS2B = {__int_as_float(M[15]), __int_as_float(M[15])};
    const int sRtA = M[16], sRtB = M[17];
    const float sRndA = __int_as_float(M[18]), sRndB = __int_as_float(M[19]);
    const int sUA = M[20], sUB = M[21];
    const float cmSA = cm[sUA]*6.f, glvSA = gleak[sUA]*vleak[sUA], cgSA = cm[sUA]*6.f + gleak[sUA] + EPS;
    const float cmSB = cm[sUB]*6.f, glvSB = gleak[sUB]*vleak[sUB], cgSB = cm[sUB]*6.f + gleak[sUB] + EPS;
    const bool ownSA = (sUA != 0), ownSB = (sUB != 0);
    const v2f initSA = ownSA ? (v2f){glvSA, cgSA} : (v2f){0.f, EPS};
    const v2f initSB = ownSB ? (v2f){glvSB, cgSB} : (v2f){0.f, EPS};
    const int iUnit = (cl < 50) ? 64 + cl : cl;
    const int iWr = iUnit * 4;
    float vIn = hidden[(size_t)b*UNITS + iUnit];
    const float iw = input_w[cl], ibv = input_b[cl];
    const float* ob = obs + (size_t)b*(TSTEPS*SDIM) + cl;

    // ---- prologue: full sensory eval for t=0 (R1 math, sw4 loads) ----
    float aI, bI;
    {
      const float xi = fmaf(ob[0], iw, ibv);
      float uu[CS];
#pragma unroll
      for (int s = 0; s < CS; ++s) {
        float z = fmaf(bperm(sad[s], xi), sNS[s], sMS[s]);
        z = fminf(z, 30.f);
        uu[s] = 1.f + __builtin_amdgcn_exp2f(z);
      }
      float sg[CS];
#pragma unroll
      for (int q = 0; q < 4; ++q) {
        const float p = uu[2*q] * uu[2*q+1];
        const float r = __builtin_amdgcn_rcpf(p);
        sg[2*q]   = uu[2*q+1] * r;
        sg[2*q+1] = uu[2*q]   * r;
      }
      sg[8] = __builtin_amdgcn_rcpf(uu[8]);
      v2f cA = {0.f,0.f}, cB = {0.f,0.f};
#pragma unroll
      for (int s = 0; s < CS; ++s) {
        const float4 wz = sw4[s*64 + cl];
        const v2f s2 = {sg[s], sg[s]};
        cA = fma2((v2f){wz.x, wz.y}, s2, cA);
        cB = fma2((v2f){wz.z, wz.w}, s2, cB);
      }
      const v2f m1 = {dperm(sPush1, cA.x), dperm(sPush1, cA.y)};
      const v2f m2 = {dperm(sPush2, cA.x), dperm(sPush2, cA.y)};
      v2f tA = fma2(gS1A, m1, cA); tA = fma2(gS2A, m2, tA);
      v2f tB = fma2(gS1B, m1, cB); tB = fma2(gS2B, m2, tB);
      const float rdA = __builtin_amdgcn_rcpf(cgSA + tA.y);
      const float aA = cmSA * rdA, bA = (glvSA + tA.x) * rdA;
      const float rdB = __builtin_amdgcn_rcpf(cgSB + tB.y);
      const float aB = cmSB * rdB, bB = (glvSB + tB.x) * rdB;
      const float ra1 = dperm(sRtA, aA), rb1 = dperm(sRtA, bA);
      const float ra2 = dperm(sRtB, aB), rb2 = dperm(sRtB, bB);
      aI = sRndA*ra1 + sRndB*ra2;
      bI = sRndA*rb1 + sRndB*rb2;
    }

    float xiN = fmaf(ob[SDIM], iw, ibv);   // xi(1)
    float xrC = ob[2*SDIM];                // obs(2)
    float su[CS];
    v2f acA = initSA, acB = initSB;
    v2f tSA = {0.f,0.f}, tSB = {0.f,0.f};
    float aIn = 0.f, bIn = 0.f;

    // rec half: 5 slots + own-partial merge -> part[cl]
    auto recHalf = [&]{
      float uu[NR1];
#pragma unroll
      for (int s = 0; s < NR1; ++s) {
        const float pv = *(const float*)(mbase + rad[s]);
        const float z = fmaf(pv, rNS[s], rMS[s]);
        uu[s] = 1.f + __builtin_amdgcn_exp2f(z);
      }
      float sg[NR1];
#pragma unroll
      for (int q = 0; q < NR1/2; ++q) {
        const float p = uu[2*q] * uu[2*q+1];
        const float r = __builtin_amdgcn_rcpf(p);
        sg[2*q]   = uu[2*q+1] * r;
        sg[2*q+1] = uu[2*q]   * r;
      }
      sg[NR1-1] = __builtin_amdgcn_rcpf(uu[NR1-1]);   // NR1 odd: solo last
      v2f a0 = {0.f,0.f}, a1 = {0.f,0.f}, b0 = {0.f,0.f}, b1 = {0.f,0.f};
#pragma unroll
      for (int s = 0; s < NR1; ++s) {
        const v2f s2 = {sg[s], sg[s]};
        if (s & 1) { a1 = fma2(rWA[s], s2, a1); b1 = fma2(rWB[s], s2, b1); }
        else       { a0 = fma2(rWA[s], s2, a0); b0 = fma2(rWB[s], s2, b0); }
      }
      const v2f pA = a0 + a1, pB = b0 + b1;
      const v2f m1 = {dperm(rPush1, pA.x), dperm(rPush1, pA.y)};
      const v2f m2 = {dperm(rPush2, pA.x), dperm(rPush2, pA.y)};
      v2f cA = fma2(gR1A, m1, pA); cA = fma2(gR2A, m2, cA);
      v2f cB = fma2(gR1B, m1, pB); cB = fma2(gR2B, m2, cB);
      part[cl] = make_float4(cA.x, cA.y, cB.x, cB.y);
    };
    auto sExp = [&](int s) {
      float z = fmaf(bperm(sad[s], xiN), sNS[s], sMS[s]);
      z = fminf(z, 30.f);       // sensory z can reach ~75 unclamped: keep
      su[s] = 1.f + __builtin_amdgcn_exp2f(z);
    };
    auto sPair = [&](int s0) {
      const float p = su[s0] * su[s0+1];
      const float r = __builtin_amdgcn_rcpf(p);
      const float g0 = su[s0+1] * r, g1 = su[s0] * r;
      const float4 wa = sw4[s0*64 + cl], wb = sw4[(s0+1)*64 + cl];
      acA = fma2((v2f){wa.x, wa.y}, (v2f){g0,g0}, acA);
      acB = fma2((v2f){wa.z, wa.w}, (v2f){g0,g0}, acB);
      acA = fma2((v2f){wb.x, wb.y}, (v2f){g1,g1}, acA);
      acB = fma2((v2f){wb.z, wb.w}, (v2f){g1,g1}, acB);
    };
    auto phase = [&](auto chunk) {
      __syncthreads();                      // A
      recHalf();
      __syncthreads();                      // B1
      vIn = fmaf(aI, vIn, bI);
      *(float*)(mbase + iWr) = vIn;
      chunk();
    };

#pragma unroll 1
    for (int t = 0; t < TSTEPS; ++t) {
      phase([&]{ sExp(0); sExp(1); });
      phase([&]{ sExp(2); sExp(3); sPair(0); });
      phase([&]{ sExp(4); sExp(5); sPair(2); });
      phase([&]{ sExp(6); sExp(7); sExp(8); sPair(4); });
      phase([&]{
        const float p67 = su[6] * su[7];
        const float r = __builtin_amdgcn_rcpf(p67 * su[8]);
        const float t67 = su[8] * r;
        const float g6 = su[7]*t67, g7 = su[6]*t67, g8 = p67*r;
        const float4 w6 = sw4[6*64 + cl], w7 = sw4[7*64 + cl], w8 = sw4[8*64 + cl];
        acA = fma2((v2f){w6.x,w6.y}, (v2f){g6,g6}, acA); acB = fma2((v2f){w6.z,w6.w}, (v2f){g6,g6}, acB);
        acA = fma2((v2f){w7.x,w7.y}, (v2f){g7,g7}, acA); acB = fma2((v2f){w7.z,w7.w}, (v2f){g7,g7}, acB);
        acA = fma2((v2f){w8.x,w8.y}, (v2f){g8,g8}, acA); acB = fma2((v2f){w8.z,w8.w}, (v2f){g8,g8}, acB);
        const v2f m1 = {dperm(sPush1, acA.x), dperm(sPush1, acA.y)};
        const v2f m2 = {dperm(sPush2, acA.x), dperm(sPush2, acA.y)};
        tSA = fma2(gS1A, m1, acA); tSA = fma2(gS2A, m2, tSA);
        tSB = fma2(gS1B, m1, acB); tSB = fma2(gS2B, m2, tSB);
      });
      phase([&]{
        const float dA_ = tSA.y, dB_ = tSB.y;
        const float rr = __builtin_amdgcn_rcpf(dA_ * dB_);
        const float rdA = dB_ * rr, rdB = dA_ * rr;
        const float aA = cmSA * rdA, bA = tSA.x * rdA;
        const float aB = cmSB * rdB, bB = tSB.x * rdB;
        const float ra1 = dperm(sRtA, aA), rb1 = dperm(sRtA, bA);
        const float ra2 = dperm(sRtB, aB), rb2 = dperm(sRtB, bB);
        aIn = sRndA*ra1 + sRndB*ra2;
        bIn = sRndA*rb1 + sRndB*rb2;
      });
      aI = aIn; bI = bIn;
      xiN = fmaf(xrC, iw, ibv);
      const int tn = (t + 3 < TSTEPS) ? (t + 3) : (TSTEPS - 1);
      xrC = ob[tn * SDIM];
      acA = initSA; acB = initSB;
    }
  }
  __syncthreads();

  // ---- outputs: h then Q head (128 lanes) ----
  float* __restrict__ outH = out + (size_t)B * ACT;
  if (tid < UNITS) outH[(size_t)b*UNITS + tid] = mirror[tid];
  float h = 0.f;
  if (tid < UNITS) {
    h = q_b1[tid];
    for (int i = 0; i < UNITS; ++i) h = fmaf(mirror[i], q_w1[i*UNITS + tid], h);
    h = fmaxf(h, 0.f);
  }
  __syncthreads();
  if (tid < UNITS) mirror[tid] = h;
  __syncthreads();
  if (tid < ACT) {
    float q = q_b2[tid];
    for (int i = 0; i < UNITS; ++i) q = fmaf(mirror[i], q_w2[i*ACT + tid], q);
    out[(size_t)b*ACT + tid] = q;
  }
}

extern "C" void kernel_launch(void* const* d_in, const int* in_sizes, int n_in,
                              void* d_out, int out_size, void* d_ws, size_t ws_size,
                              hipStream_t stream)
{
  const float* obs           = (const float*)d_in[0];
  const float* hidden        = (const float*)d_in[1];
  const float* input_w       = (const float*)d_in[2];
  const float* input_b       = (const float*)d_in[3];
  const float* sensory_w     = (const float*)d_in[4];
  const float* sensory_mu    = (const float*)d_in[5];
  const float* sensory_sigma = (const float*)d_in[6];
  const float* sensory_erev  = (const float*)d_in[7];
  const float* sensory_mask  = (const float*)d_in[8];
  const float* w             = (const float*)d_in[9];
  const float* mu            = (const float*)d_in[10];
  const float* sigma         = (const float*)d_in[11];
  const float* erev          = (const float*)d_in[12];
  const float* mask          = (const float*)d_in[13];
  const float* gleak         = (const float*)d_in[14];
  const float* vleak         = (const float*)d_in[15];
  const float* cm            = (const float*)d_in[16];
  const float* q_w1          = (const float*)d_in[17];
  const float* q_b1          = (const float*)d_in[18];
  const float* q_w2          = (const float*)d_in[19];
  const float* q_b2          = (const float*)d_in[20];

  char* ws = (char*)d_ws;
  float4* recP4 = (float4*)(ws);            // 13*64*16 = 13312
  float2* recP2 = (float2*)(ws + 13312);    // 13*64*8  = 6656  -> 19968
  int*    recAd = (int*)   (ws + 19968);    // 13*64*4  = 3328  -> 23296
  float4* senP4 = (float4*)(ws + 23296);    // 9*64*16  = 9216  -> 32512
  float2* senP2 = (float2*)(ws + 32512);    // 9*64*8   = 4608  -> 37120
  int*    senAd = (int*)   (ws + 37120);    // 9*64*4   = 2304  -> 39424
  int*    meta  = (int*)   (ws + 39424);    // 64*24*4  = 6144  -> 45568

  build_all<<<8, 64, 0, stream>>>(
      w, mu, sigma, erev, mask,
      sensory_w, sensory_mu, sensory_sigma, sensory_erev, sensory_mask,
      recP4, recP2, recAd, senP4, senP2, senAd, meta);

  const int B = in_sizes[0] / (TSTEPS * SDIM);
  ltc_run<<<B, 128, 0, stream>>>(
      obs, hidden, input_w, input_b, gleak, vleak, cm,
      q_w1, q_b1, q_w2, q_b2,
      recP4, recP2, recAd, senP4, senP2, senAd, meta,
      (float*)d_out, B);
}

// Round 7
// 354.882 us; speedup vs baseline: 1.1472x; 1.1472x over previous
//
#include <hip/hip_runtime.h>

#define UNITS   114
#define SDIM    64
#define ACT     18
#define TSTEPS  64

// Bin-packed slots (placement identical to R1):
//   rec: E <= 704 edges, C=13/lane, <=2 posts/lane, <=3 lanes/post.
//   sensory: E == 512, C=9.
#define CR 13
#define CS 9
#define MSTRIDE 24

#define LOG2E 1.4426950408889634f
#define EPS   1e-8f

typedef float v2f __attribute__((ext_vector_type(2)));
__device__ __forceinline__ v2f fma2(v2f a, v2f b, v2f c) {
  return __builtin_elementwise_fma(a, b, c);
}
__device__ __forceinline__ float bperm(int addr, float v) {
  return __int_as_float(__builtin_amdgcn_ds_bpermute(addr, __float_as_int(v)));
}
__device__ __forceinline__ float dperm(int addr, float v) {   // push: lane[addr>>2] <- v
  return __int_as_float(__builtin_amdgcn_ds_permute(addr, __float_as_int(v)));
}
__device__ __forceinline__ void wsync() {
  __builtin_amdgcn_fence(__ATOMIC_ACQ_REL, "wavefront");
  __builtin_amdgcn_wave_barrier();
}
__device__ __forceinline__ int canonLane(int u) { return (u >= 64) ? (u - 64) : u; }

// k-th set bit of a 64-bit mask (k 0-based).
__device__ __forceinline__ int kthSetBit(unsigned long long m, int k) {
  int pos = 0;
#pragma unroll
  for (int ww = 32; ww >= 1; ww >>= 1) {
    const unsigned long long lowMask = ((1ull << ww) - 1ull);
    const int c = __popcll(m & lowMask);
    if (k >= c) { k -= c; m >>= ww; pos += ww; }
  }
  return pos;
}
__device__ __forceinline__ unsigned long long shfl_u64(unsigned long long v, int src) {
  const int lo = __shfl((int)(unsigned)(v & 0xffffffffull), src);
  const int hi = __shfl((int)(unsigned)(v >> 32), src);
  return ((unsigned long long)(unsigned)hi << 32) | (unsigned)lo;
}

// ---------------------------------------------------------------------------
// Build (R5 verbatim, proven fast + bit-identical tables).
// ---------------------------------------------------------------------------
__global__ __launch_bounds__(64) void build_all(
    const float* __restrict__ w,  const float* __restrict__ mu,
    const float* __restrict__ sigma, const float* __restrict__ erev,
    const float* __restrict__ mask,
    const float* __restrict__ sw, const float* __restrict__ smu,
    const float* __restrict__ ssg, const float* __restrict__ serev,
    const float* __restrict__ smask,
    float4* __restrict__ recP4, float2* __restrict__ recP2, int* __restrict__ recAd,
    float4* __restrict__ senP4, float2* __restrict__ senP2, int* __restrict__ senAd,
    int* __restrict__ meta)
{
  const int l = threadIdx.x;
  const int bid = blockIdx.x;
  __shared__ int degL[64], pF0L[64];
  __shared__ int contIdx[64], contOwn[64], splitRole[64], split2[64], ownP[128];
  __shared__ int rcv[64];

  contIdx[l] = 0; contOwn[l] = 0; splitRole[l] = -1; split2[l] = 0;
  ownP[2*l] = -1; ownP[2*l+1] = -1;

  if (bid < 4) {
    // ================= REC family =================
    unsigned long long cLo = 0ull, cHi = 0ull;
    if (l < 50) {
      for (int base = 0; base < 64; base += 16) {
        float mv[16];
#pragma unroll
        for (int q = 0; q < 16; ++q) mv[q] = mask[(18 + base + q)*UNITS + l];
#pragma unroll
        for (int q = 0; q < 16; ++q) if (mv[q] != 0.f) cLo |= (1ull << (base + q));
      }
      for (int base = 0; base < 32; base += 16) {
        float mv[16];
#pragma unroll
        for (int q = 0; q < 16; ++q) mv[q] = mask[(82 + base + q)*UNITS + l];
#pragma unroll
        for (int q = 0; q < 16; ++q) if (mv[q] != 0.f) cHi |= (1ull << (base + q));
      }
    }
    const int dreg = __popcll(cLo) + __popcll(cHi);
    degL[l] = dreg;
    wsync();
    {
      int lam = 0, f = 0, pc = 0;
      for (int p = 0; p < 50; ++p) {
        const int dd = __shfl(dreg, p);
        if (pc == 2 || f == CR || dd > 3*CR - f) { ++lam; f = 0; pc = 0; }
        if (lam > 63) lam = 63;
        if (l == 0) { pF0L[p] = f; ownP[2*lam + pc] = p; }
        const int owner = lam, role = pc; ++pc;
        const int take = dd < (CR - f) ? dd : (CR - f);
        f += take; int rem = dd - take;
        if (rem > 0) {
          if (l == 0) { splitRole[owner] = role; split2[owner] = (rem > CR) ? 1 : 0; }
          ++lam; if (lam > 63) lam = 63;
          if (l == 0) { contIdx[lam] = 1; contOwn[lam] = owner; }
          pc = 1;
          const int t2 = rem < CR ? rem : CR; f = t2; rem -= t2;
          if (rem > 0) {
            ++lam; if (lam > 63) lam = 63;
            if (l == 0) { contIdx[lam] = 2; contOwn[lam] = owner; }
            pc = 1; f = rem;
          }
        }
      }
    }
    wsync();
    int dAr = (contIdx[l] == 1) ? contOwn[l] : -1;
    int dBr = (contIdx[l] == 2) ? contOwn[l] : -1;
    rcv[l] = 0; wsync();
    if (dAr >= 0) rcv[dAr] = 1;
    wsync();
    { const unsigned long long rM = __ballot(rcv[l] != 0), dM = __ballot(dAr < 0);
      if (dAr < 0) dAr = kthSetBit(~rM, __popcll(dM & ((1ull << l) - 1ull))); }
    wsync();
    rcv[l] = 0; wsync();
    if (dBr >= 0) rcv[dBr] = 1;
    wsync();
    { const unsigned long long rM = __ballot(rcv[l] != 0), dM = __ballot(dBr < 0);
      if (dBr < 0) dBr = kthSetBit(~rM, __popcll(dM & ((1ull << l) - 1ull))); }
    const int uA = ownP[2*l], uB = ownP[2*l+1];
    if (bid == 0) {
      int* M = meta + l * MSTRIDE;
      M[0] = dAr * 4; M[1] = dBr * 4;
      const float s1A = (splitRole[l] == 0) ? 1.f : 0.f, s1B = (splitRole[l] == 1) ? 1.f : 0.f;
      M[2] = __float_as_int(s1A); M[3] = __float_as_int(s1B);
      const float s2 = split2[l] ? 1.f : 0.f;
      M[4] = __float_as_int(s1A * s2); M[5] = __float_as_int(s1B * s2);
      M[6] = ((uA >= 0) ? uA : 128 + l) * 4;
      M[7] = ((uB >= 0) ? uB : 192 + l) * 4;
      M[8] = (uA >= 0) ? uA : 0;
      M[9] = (uB >= 0) ? uB : 0;
    }
    const int ci = contIdx[l];
    int p1 = -1, br = 0, cnt1 = 0;
    if (ci) {
      const int o = contOwn[l];
      p1 = ownP[2*o + splitRole[o]];
      br = (CR - pF0L[p1]) + ((ci == 2) ? CR : 0);
      cnt1 = degL[p1] - br; if (cnt1 > CR) cnt1 = CR;
    }
    int fA = 0, tA = -1;
    if (uA >= 0) { fA = pF0L[uA]; const int rm = CR - fA; const int dd = degL[uA]; tA = dd < rm ? dd : rm; }
    int fB = 0, tB = -1;
    if (uB >= 0) { fB = pF0L[uB]; const int rm = CR - fB; const int dd = degL[uB]; tB = dd < rm ? dd : rm; }
    for (int s = bid; s < CR; s += 4) {
      int post = -1, rank = 0, isB = 0;
      if (ci && s < cnt1)                          { post = p1; rank = br + s; }
      else if (uA >= 0 && s >= fA && s < fA + tA)  { post = uA; rank = s - fA; }
      else if (uB >= 0 && s >= fB && s < fB + tB)  { post = uB; rank = s - fB; isB = 1; }
      const int postc = (post >= 0) ? post : 0;
      const unsigned long long plo = shfl_u64(cLo, postc);
      const unsigned long long phi = shfl_u64(cHi, postc);
      float4 p4 = make_float4(0.f, 0.f, 0.f, 0.f);
      float2 p2 = make_float2(0.f, 0.f);
      int ad = 0;
      if (post >= 0) {
        const int c = __popcll(plo);
        const int pre = (rank < c) ? (18 + kthSetBit(plo, rank)) : (82 + kthSetBit(phi, rank - c));
        const int idx = pre * UNITS + post;
        const float sg_ = sigma[idx];
        const float nsgl = -sg_ * LOG2E, msl = mu[idx] * sg_ * LOG2E;
        const float wd = w[idx], wn = wd * erev[idx];
        p4 = make_float4(nsgl, msl, isB ? 0.f : wn, isB ? 0.f : wd);
        p2 = isB ? make_float2(wn, wd) : make_float2(0.f, 0.f);
        ad = pre * 4;
      }
      recP4[s*64 + l] = p4; recP2[s*64 + l] = p2; recAd[s*64 + l] = ad;
    }
  } else {
    // ================= SENSORY family =================
    unsigned long long cS = 0ull;
    {
      const int col = 50 + l;
      for (int base = 0; base < 64; base += 16) {
        float mv[16];
#pragma unroll
        for (int q = 0; q < 16; ++q) mv[q] = smask[(base + q)*UNITS + col];
#pragma unroll
        for (int q = 0; q < 16; ++q) if (mv[q] != 0.f) cS |= (1ull << (base + q));
      }
    }
    const int dreg = __popcll(cS);
    degL[l] = dreg;
    wsync();
    {
      int lam = 0, f = 0, pc = 0;
      for (int p = 0; p < 64; ++p) {
        const int dd = __shfl(dreg, p);
        if (pc == 2 || f == CS || dd > 3*CS - f) { ++lam; f = 0; pc = 0; }
        if (lam > 63) lam = 63;
        if (l == 0) { pF0L[p] = f; ownP[2*lam + pc] = p; }
        const int owner = lam, role = pc; ++pc;
        const int take = dd < (CS - f) ? dd : (CS - f);
        f += take; int rem = dd - take;
        if (rem > 0) {
          if (l == 0) { splitRole[owner] = role; split2[owner] = (rem > CS) ? 1 : 0; }
          ++lam; if (lam > 63) lam = 63;
          if (l == 0) { contIdx[lam] = 1; contOwn[lam] = owner; }
          pc = 1;
          const int t2 = rem < CS ? rem : CS; f = t2; rem -= t2;
          if (rem > 0) {
            ++lam; if (lam > 63) lam = 63;
            if (l == 0) { contIdx[lam] = 2; contOwn[lam] = owner; }
            pc = 1; f = rem;
          }
        }
      }
    }
    wsync();
    int dAs = (contIdx[l] == 1) ? contOwn[l] : -1;
    int dBs = (contIdx[l] == 2) ? contOwn[l] : -1;
    rcv[l] = 0; wsync();
    if (dAs >= 0) rcv[dAs] = 1;
    wsync();
    { const unsigned long long rM = __ballot(rcv[l] != 0), dM = __ballot(dAs < 0);
      if (dAs < 0) dAs = kthSetBit(~rM, __popcll(dM & ((1ull << l) - 1ull))); }
    wsync();
    rcv[l] = 0; wsync();
    if (dBs >= 0) rcv[dBs] = 1;
    wsync();
    { const unsigned long long rM = __ballot(rcv[l] != 0), dM = __ballot(dBs < 0);
      if (dBs < 0) dBs = kthSetBit(~rM, __popcll(dM & ((1ull << l) - 1ull))); }
    wsync();
    int rAs = (ownP[2*l]   >= 0) ? canonLane(50 + ownP[2*l])   : -1;
    int rBs = (ownP[2*l+1] >= 0) ? canonLane(50 + ownP[2*l+1]) : -1;
    rcv[l] = 0; wsync();
    if (rAs >= 0) rcv[rAs] = 1;
    wsync();
    const int isRcvA = rcv[l];
    { const unsigned long long rM = __ballot(isRcvA != 0), dM = __ballot(rAs < 0);
      if (rAs < 0) rAs = kthSetBit(~rM, __popcll(dM & ((1ull << l) - 1ull))); }
    wsync();
    rcv[l] = 0; wsync();
    if (rBs >= 0) rcv[rBs] = 1;
    wsync();
    { const unsigned long long rM = __ballot(rcv[l] != 0), dM = __ballot(rBs < 0);
      if (rBs < 0) rBs = kthSetBit(~rM, __popcll(dM & ((1ull << l) - 1ull))); }
    const int pAs = ownP[2*l], pBs = ownP[2*l+1];
    if (bid == 4) {
      int* M = meta + l * MSTRIDE;
      M[10] = dAs * 4; M[11] = dBs * 4;
      const float s1A = (splitRole[l] == 0) ? 1.f : 0.f, s1B = (splitRole[l] == 1) ? 1.f : 0.f;
      M[12] = __float_as_int(s1A); M[13] = __float_as_int(s1B);
      const float s2 = split2[l] ? 1.f : 0.f;
      M[14] = __float_as_int(s1A * s2); M[15] = __float_as_int(s1B * s2);
      M[16] = rAs * 4; M[17] = rBs * 4;
      M[18] = __float_as_int(isRcvA ? 1.f : 0.f);
      M[19] = __float_as_int(isRcvA ? 0.f : 1.f);
      M[20] = (pAs >= 0) ? 50 + pAs : 0;
      M[21] = (pBs >= 0) ? 50 + pBs : 0;
    }
    const int ci = contIdx[l];
    int p1 = -1, br = 0, cnt1 = 0;
    if (ci) {
      const int o = contOwn[l];
      p1 = ownP[2*o + splitRole[o]];
      br = (CS - pF0L[p1]) + ((ci == 2) ? CS : 0);
      cnt1 = degL[p1] - br; if (cnt1 > CS) cnt1 = CS;
    }
    int fA = 0, tA = -1;
    if (pAs >= 0) { fA = pF0L[pAs]; const int rm = CS - fA; const int dd = degL[pAs]; tA = dd < rm ? dd : rm; }
    int fB = 0, tB = -1;
    if (pBs >= 0) { fB = pF0L[pBs]; const int rm = CS - fB; const int dd = degL[pBs]; tB = dd < rm ? dd : rm; }
    for (int s = bid - 4; s < CS; s += 4) {
      int post = -1, rank = 0, isB = 0;
      if (ci && s < cnt1)                            { post = p1;  rank = br + s; }
      else if (pAs >= 0 && s >= fA && s < fA + tA)   { post = pAs; rank = s - fA; }
      else if (pBs >= 0 && s >= fB && s < fB + tB)   { post = pBs; rank = s - fB; isB = 1; }
      const int postc = (post >= 0) ? post : 0;
      const unsigned long long pm = shfl_u64(cS, postc);
      float4 p4 = make_float4(0.f, 0.f, 0.f, 0.f);
      float2 p2 = make_float2(0.f, 0.f);
      int ad = 0;
      if (post >= 0) {
        const int pre = kthSetBit(pm, rank);
        const int idx = pre * UNITS + 50 + post;
        const float sg_ = ssg[idx];
        const float nsgl = -sg_ * LOG2E, msl = smu[idx] * sg_ * LOG2E;
        const float wd = sw[idx], wn = wd * serev[idx];
        p4 = make_float4(nsgl, msl, isB ? 0.f : wn, isB ? 0.f : wd);
        p2 = isB ? make_float2(wn, wd) : make_float2(0.f, 0.f);
        ad = pre * 4;
      }
      senP4[s*64 + l] = p4; senP2[s*64 + l] = p2; senAd[s*64 + l] = ad;
    }
  }
}

// ---------------------------------------------------------------------------
// Run kernel: R5 verbatim + s_setprio(1) around the rec tail (T5, attn-case
// mechanism: independent 1-wave blocks; the tail is a ~100cy serial chain
// dperm->merge->rcp->state->writes; priority lets this wave win issue
// arbitration the moment operands return, taking slack from the co-resident
// wave's latency-tolerant read/exp phase). Zero numeric change.
// ---------------------------------------------------------------------------
__global__ __launch_bounds__(64, 2) void ltc_run(
    const float* __restrict__ obs,     const float* __restrict__ hidden,
    const float* __restrict__ input_w, const float* __restrict__ input_b,
    const float* __restrict__ gleak,   const float* __restrict__ vleak,
    const float* __restrict__ cm,
    const float* __restrict__ q_w1, const float* __restrict__ q_b1,
    const float* __restrict__ q_w2, const float* __restrict__ q_b2,
    const float4* __restrict__ recP4, const float2* __restrict__ recP2,
    const int* __restrict__ recAd,
    const float4* __restrict__ senP4, const float2* __restrict__ senP2,
    const int* __restrict__ senAd,
    const int* __restrict__ meta, float* __restrict__ out, int B)
{
  const int l = threadIdx.x, b = blockIdx.x;
  __shared__ float mirror[256];   // [0..113] units, [128..255] scratch sinks
  char* mbase = (char*)mirror;

  float rNS[CR], rMS[CR]; v2f rWA[CR], rWB[CR]; int rad[CR];
#pragma unroll
  for (int s = 0; s < CR; ++s) {
    const float4 p4 = recP4[s*64 + l]; const float2 p2 = recP2[s*64 + l];
    rNS[s] = p4.x; rMS[s] = p4.y; rWA[s] = (v2f){p4.z, p4.w};
    rWB[s] = (v2f){p2.x, p2.y}; rad[s] = recAd[s*64 + l];
  }
  float sNS[CS], sMS[CS]; v2f sWA[CS], sWB[CS]; int sad[CS];
#pragma unroll
  for (int s = 0; s < CS; ++s) {
    const float4 p4 = senP4[s*64 + l]; const float2 p2 = senP2[s*64 + l];
    sNS[s] = p4.x; sMS[s] = p4.y; sWA[s] = (v2f){p4.z, p4.w};
    sWB[s] = (v2f){p2.x, p2.y}; sad[s] = senAd[s*64 + l];
  }

  const int* M = meta + l * MSTRIDE;
  const int   rPush1 = M[0], rPush2 = M[1];
  const v2f gR1A = {__int_as_float(M[2]), __int_as_float(M[2])};
  const v2f gR1B = {__int_as_float(M[3]), __int_as_float(M[3])};
  const v2f gR2A = {__int_as_float(M[4]), __int_as_float(M[4])};
  const v2f gR2B = {__int_as_float(M[5]), __int_as_float(M[5])};
  const int   rWrA = M[6], rWrB = M[7], rUA = M[8], rUB = M[9];
  const int   sPush1 = M[10], sPush2 = M[11];
  const v2f gS1A = {__int_as_float(M[12]), __int_as_float(M[12])};
  const v2f gS1B = {__int_as_float(M[13]), __int_as_float(M[13])};
  const v2f gS2A = {__int_as_float(M[14]), __int_as_float(M[14])};
  const v2f gS2B = {__int_as_float(M[15]), __int_as_float(M[15])};
  const int   sRtA = M[16], sRtB = M[17];
  const float sRndA = __int_as_float(M[18]), sRndB = __int_as_float(M[19]);
  const int   sUA = M[20], sUB = M[21];

  const float cmA  = cm[rUA]*6.f, glvA  = gleak[rUA]*vleak[rUA], cgA  = cm[rUA]*6.f + gleak[rUA] + EPS;
  const float cmB  = cm[rUB]*6.f, glvB  = gleak[rUB]*vleak[rUB], cgB  = cm[rUB]*6.f + gleak[rUB] + EPS;
  const float cmSA = cm[sUA]*6.f, glvSA = gleak[sUA]*vleak[sUA], cgSA = cm[sUA]*6.f + gleak[sUA] + EPS;
  const float cmSB = cm[sUB]*6.f, glvSB = gleak[sUB]*vleak[sUB], cgSB = cm[sUB]*6.f + gleak[sUB] + EPS;

  const bool ownA  = (rWrA < 512), ownB  = (rWrB < 512);
  const bool ownSA = (sUA != 0),   ownSB = (sUB != 0);
  const v2f initRA = ownA  ? (v2f){glvA,  cgA}  : (v2f){0.f, EPS};
  const v2f initRB = ownB  ? (v2f){glvB,  cgB}  : (v2f){0.f, EPS};
  const v2f initSA = ownSA ? (v2f){glvSA, cgSA} : (v2f){0.f, EPS};
  const v2f initSB = ownSB ? (v2f){glvSB, cgSB} : (v2f){0.f, EPS};

  const int  iUnit = (l < 50) ? 64 + l : l;
  const int  iWr   = iUnit * 4;
  float vIn = hidden[(size_t)b*UNITS + iUnit];
  float vPA = hidden[(size_t)b*UNITS + rUA];
  float vPB = hidden[(size_t)b*UNITS + rUB];

  mirror[l] = hidden[(size_t)b*UNITS + l];
  if (l < 50) mirror[64 + l] = hidden[(size_t)b*UNITS + 64 + l];

  const float iw = input_w[l], ibv = input_b[l];
  const float* ob = obs + (size_t)b*(TSTEPS*SDIM) + l;

  // ---- prologue: full sensory eval for t=0 ----
  float aI, bI;
  {
    const float xi = fmaf(ob[0], iw, ibv);
    float uu[CS];
#pragma unroll
    for (int s = 0; s < CS; ++s) {
      float z = fmaf(bperm(sad[s], xi), sNS[s], sMS[s]);
      z = fminf(z, 30.f);
      uu[s] = 1.f + __builtin_amdgcn_exp2f(z);
    }
    float sg[CS];
#pragma unroll
    for (int q = 0; q < 4; ++q) {
      const float p = uu[2*q] * uu[2*q+1];
      const float r = __builtin_amdgcn_rcpf(p);
      sg[2*q]   = uu[2*q+1] * r;
      sg[2*q+1] = uu[2*q]   * r;
    }
    sg[8] = __builtin_amdgcn_rcpf(uu[8]);
    v2f cA = {0.f,0.f}, cB = {0.f,0.f};
#pragma unroll
    for (int s = 0; s < CS; ++s) {
      const v2f s2 = {sg[s], sg[s]};
      cA = fma2(sWA[s], s2, cA);
      cB = fma2(sWB[s], s2, cB);
    }
    const v2f m1 = {dperm(sPush1, cA.x), dperm(sPush1, cA.y)};
    const v2f m2 = {dperm(sPush2, cA.x), dperm(sPush2, cA.y)};
    v2f tA = fma2(gS1A, m1, cA); tA = fma2(gS2A, m2, tA);
    v2f tB = fma2(gS1B, m1, cB); tB = fma2(gS2B, m2, tB);
    const float rdA = __builtin_amdgcn_rcpf(cgSA + tA.y);
    const float aA = cmSA * rdA, bA = (glvSA + tA.x) * rdA;
    const float rdB = __builtin_amdgcn_rcpf(cgSB + tB.y);
    const float aB = cmSB * rdB, bB = (glvSB + tB.x) * rdB;
    const float ra1 = dperm(sRtA, aA), rb1 = dperm(sRtA, bA);
    const float ra2 = dperm(sRtB, aB), rb2 = dperm(sRtB, bB);
    aI = sRndA*ra1 + sRndB*ra2;
    bI = sRndA*rb1 + sRndB*rb2;
  }

  float xiN = fmaf(ob[SDIM], iw, ibv);   // xi(1)
  float xrC = ob[2*SDIM];                // obs(2)
  float su[CS];
  v2f acA = initSA, acB = initSB;
  v2f tSA = {0.f,0.f}, tSB = {0.f,0.f};
  float aIn = 0.f, bIn = 0.f;

  auto unfold = [&](auto chunk) {
    wsync();
    float uu[CR];
#pragma unroll
    for (int s = 0; s < CR; ++s) {
      const float pv = *(const float*)(mbase + rad[s]);
      const float z = fmaf(pv, rNS[s], rMS[s]);   // z <= 20.8 always: no clamp
      uu[s] = 1.f + __builtin_amdgcn_exp2f(z);
    }
    chunk();
    float sg[CR];
#pragma unroll
    for (int q = 0; q < 5; ++q) {
      const float p = uu[2*q] * uu[2*q+1];
      const float r = __builtin_amdgcn_rcpf(p);
      sg[2*q]   = uu[2*q+1] * r;
      sg[2*q+1] = uu[2*q]   * r;
    }
    {   // triple-shared rcp for slots 10,11,12
      const float p01 = uu[10]*uu[11];
      const float r = __builtin_amdgcn_rcpf(p01*uu[12]);
      const float t12 = uu[12]*r;
      sg[10] = uu[11]*t12; sg[11] = uu[10]*t12; sg[12] = p01*r;
    }
    v2f a0 = initRA, a1 = {0.f,0.f}, b0 = initRB, b1 = {0.f,0.f};
#pragma unroll
    for (int s = 0; s < CR; ++s) {
      const v2f s2 = {sg[s], sg[s]};
      if (s & 1) { a1 = fma2(rWA[s], s2, a1); b1 = fma2(rWB[s], s2, b1); }
      else       { a0 = fma2(rWA[s], s2, a0); b0 = fma2(rWB[s], s2, b0); }
    }
    v2f aA = a0 + a1, aB = b0 + b1;
    __builtin_amdgcn_s_setprio(1);      // rec tail: serial dperm->merge->state
    const v2f m1 = {dperm(rPush1, aA.x), dperm(rPush1, aA.y)};
    const v2f m2 = {dperm(rPush2, aA.x), dperm(rPush2, aA.y)};
    v2f tA = fma2(gR1A, m1, aA); tA = fma2(gR2A, m2, tA);
    v2f tB = fma2(gR1B, m1, aB); tB = fma2(gR2B, m2, tB);
    const float dAq = tA.y, dBq = tB.y;
    const float rr = __builtin_amdgcn_rcpf(dAq * dBq);
    vPA = fmaf(cmA, vPA, tA.x) * (dBq * rr);
    vPB = fmaf(cmB, vPB, tB.x) * (dAq * rr);
    vIn = fmaf(aI, vIn, bI);
    wsync();
    *(float*)(mbase + rWrA) = vPA;
    *(float*)(mbase + rWrB) = vPB;
    *(float*)(mbase + iWr)  = vIn;
    __builtin_amdgcn_s_setprio(0);      // back to normal for reads/chunk phase
  };

  auto sExp = [&](int s) {
    float z = fmaf(bperm(sad[s], xiN), sNS[s], sMS[s]);
    z = fminf(z, 30.f);         // KEEP: sensory z can reach ~75 unclamped
    su[s] = 1.f + __builtin_amdgcn_exp2f(z);
  };
  auto sPair = [&](int s0) {
    const float p = su[s0] * su[s0+1];
    const float r = __builtin_amdgcn_rcpf(p);
    const float g0 = su[s0+1] * r, g1 = su[s0] * r;
    acA = fma2(sWA[s0],   (v2f){g0,g0}, acA);
    acA = fma2(sWA[s0+1], (v2f){g1,g1}, acA);
    acB = fma2(sWB[s0],   (v2f){g0,g0}, acB);
    acB = fma2(sWB[s0+1], (v2f){g1,g1}, acB);
  };

#pragma unroll 1
  for (int t = 0; t < TSTEPS; ++t) {
    unfold([&]{ sExp(0); sExp(1); });
    unfold([&]{ sExp(2); sExp(3); sPair(0); });
    unfold([&]{ sExp(4); sExp(5); sPair(2); });
    unfold([&]{ sExp(6); sExp(7); sExp(8); sPair(4); });
    unfold([&]{
      const float p67 = su[6] * su[7];
      const float r = __builtin_amdgcn_rcpf(p67 * su[8]);
      const float t67 = su[8] * r;
      const float g6 = su[7]*t67, g7 = su[6]*t67, g8 = p67*r;
      acA = fma2(sWA[6], (v2f){g6,g6}, acA); acB = fma2(sWB[6], (v2f){g6,g6}, acB);
      acA = fma2(sWA[7], (v2f){g7,g7}, acA); acB = fma2(sWB[7], (v2f){g7,g7}, acB);
      acA = fma2(sWA[8], (v2f){g8,g8}, acA); acB = fma2(sWB[8], (v2f){g8,g8}, acB);
      const v2f m1 = {dperm(sPush1, acA.x), dperm(sPush1, acA.y)};
      const v2f m2 = {dperm(sPush2, acA.x), dperm(sPush2, acA.y)};
      tSA = fma2(gS1A, m1, acA); tSA = fma2(gS2A, m2, tSA);
      tSB = fma2(gS1B, m1, acB); tSB = fma2(gS2B, m2, tSB);
    });
    unfold([&]{
      const float dA_ = tSA.y, dB_ = tSB.y;
      const float rr = __builtin_amdgcn_rcpf(dA_ * dB_);
      const float rdA = dB_ * rr, rdB = dA_ * rr;
      const float aA = cmSA * rdA, bA = tSA.x * rdA;
      const float aB = cmSB * rdB, bB = tSB.x * rdB;
      const float ra1 = dperm(sRtA, aA), rb1 = dperm(sRtA, bA);
      const float ra2 = dperm(sRtB, aB), rb2 = dperm(sRtB, bB);
      aIn = sRndA*ra1 + sRndB*ra2;
      bIn = sRndA*rb1 + sRndB*rb2;
    });
    aI = aIn; bI = bIn;
    xiN = fmaf(xrC, iw, ibv);                      // xi(t+2)
    const int tn = (t + 3 < TSTEPS) ? (t + 3) : (TSTEPS - 1);
    xrC = ob[tn * SDIM];                           // obs(t+3), clamped
    acA = initSA; acB = initSB;
  }
  wsync();

  // ---- outputs: h then Q head ----
  float* __restrict__ outH = out + (size_t)B * ACT;
  outH[(size_t)b*UNITS + l] = mirror[l];
  if (l < 50) outH[(size_t)b*UNITS + 64 + l] = mirror[64 + l];

  const int j2 = (l < 50) ? 64 + l : l;
  float h1 = q_b1[l], h2 = q_b1[j2];
  for (int i = 0; i < UNITS; ++i) {
    const float hv = mirror[i];
    h1 = fmaf(hv, q_w1[i*UNITS + l],  h1);
    h2 = fmaf(hv, q_w1[i*UNITS + j2], h2);
  }
  h1 = fmaxf(h1, 0.f); h2 = fmaxf(h2, 0.f);
  wsync();
  mirror[l] = h1;
  if (l < 50) mirror[64 + l] = h2;
  wsync();
  if (l < ACT) {
    float q = q_b2[l];
    for (int i = 0; i < UNITS; ++i) q = fmaf(mirror[i], q_w2[i*ACT + l], q);
    out[(size_t)b*ACT + l] = q;
  }
}

extern "C" void kernel_launch(void* const* d_in, const int* in_sizes, int n_in,
                              void* d_out, int out_size, void* d_ws, size_t ws_size,
                              hipStream_t stream)
{
  const float* obs           = (const float*)d_in[0];
  const float* hidden        = (const float*)d_in[1];
  const float* input_w       = (const float*)d_in[2];
  const float* input_b       = (const float*)d_in[3];
  const float* sensory_w     = (const float*)d_in[4];
  const float* sensory_mu    = (const float*)d_in[5];
  const float* sensory_sigma = (const float*)d_in[6];
  const float* sensory_erev  = (const float*)d_in[7];
  const float* sensory_mask  = (const float*)d_in[8];
  const float* w             = (const float*)d_in[9];
  const float* mu            = (const float*)d_in[10];
  const float* sigma         = (const float*)d_in[11];
  const float* erev          = (const float*)d_in[12];
  const float* mask          = (const float*)d_in[13];
  const float* gleak         = (const float*)d_in[14];
  const float* vleak         = (const float*)d_in[15];
  const float* cm            = (const float*)d_in[16];
  const float* q_w1          = (const float*)d_in[17];
  const float* q_b1          = (const float*)d_in[18];
  const float* q_w2          = (const float*)d_in[19];
  const float* q_b2          = (const float*)d_in[20];

  char* ws = (char*)d_ws;
  float4* recP4 = (float4*)(ws);            // 13*64*16 = 13312
  float2* recP2 = (float2*)(ws + 13312);    // 13*64*8  = 6656  -> 19968
  int*    recAd = (int*)   (ws + 19968);    // 13*64*4  = 3328  -> 23296
  float4* senP4 = (float4*)(ws + 23296);    // 9*64*16  = 9216  -> 32512
  float2* senP2 = (float2*)(ws + 32512);    // 9*64*8   = 4608  -> 37120
  int*    senAd = (int*)   (ws + 37120);    // 9*64*4   = 2304  -> 39424
  int*    meta  = (int*)   (ws + 39424);    // 64*24*4  = 6144  -> 45568

  build_all<<<8, 64, 0, stream>>>(
      w, mu, sigma, erev, mask,
      sensory_w, sensory_mu, sensory_sigma, sensory_erev, sensory_mask,
      recP4, recP2, recAd, senP4, senP2, senAd, meta);

  const int B = in_sizes[0] / (TSTEPS * SDIM);
  ltc_run<<<B, 64, 0, stream>>>(
      obs, hidden, input_w, input_b, gleak, vleak, cm,
      q_w1, q_b1, q_w2, q_b2,
      recP4, recP2, recAd, senP4, senP2, senAd, meta,
      (float*)d_out, B);
}